// Round 14
// baseline (246.181 us; speedup 1.0000x reference)
//
#include <hip/hip_runtime.h>
#include <hip/hip_bf16.h>

typedef __attribute__((ext_vector_type(8))) short bf16x8;
typedef __attribute__((ext_vector_type(4))) short short4v;
typedef __attribute__((ext_vector_type(4))) float f32x4;
typedef __attribute__((ext_vector_type(4))) float float4v;
typedef __attribute__((ext_vector_type(4))) int int4v;

constexpr int L0 = 360, L2n = 90, L3n = 45;
constexpr int SD = 67, NQ = 2278, LIB = 2480, FCIN = 2880;
constexpr int C1_CH = 20, S1B = 186 * C1_CH * 2;   // 7440
constexpr int C2_CH = 44, S2B = 96 * C2_CH * 2;    // 8448
constexpr int S3E = 2888;                          // c3 elems/sample (m' = t*64+o)
constexpr int XB_STRIDE = 392;

// ---------- kernel A (conv pipeline) LDS ----------
constexpr int A_C3 = 0;                 // [2][2888] bf16, XOR-swizzled
constexpr int A_C3SZ = 2 * S3E * 2;     // 11552
constexpr int A_C1 = A_C3 + A_C3SZ;     // 11552
constexpr int A_C1SZ = 2 * S1B;         // 14880
constexpr int A_C2 = A_C1 + A_C1SZ;     // 26432
constexpr int A_C2SZ = 2 * S2B + 512;   // 17408 (pad absorbs tail garbage reads)
constexpr int A_XB = A_C2 + A_C2SZ;     // 43840
constexpr int A_XBSZ = 2 * XB_STRIDE * 2;  // 1568
constexpr int A_PAR = A_XB + A_XBSZ;    // 45408 ; f32 b1[16] b2[32] b3[64]
constexpr int A_SMEM = A_PAR + 448;     // 45856  -> 2 blocks/CU easily
static_assert(A_SMEM <= 81920, "A LDS over 2-block budget");

// ---------- kernel B (fc + quad + tail) LDS ----------
constexpr int B_ST = 0;                 // [64][68] f32 (cols 0..63 used)
constexpr int B_STSZ = 64 * 68 * 4;     // 17408
constexpr int B_SB = B_ST + B_STSZ;     // [64][104] bf16
constexpr int B_SBSZ = 64 * 104 * 2;    // 13312
constexpr int B_YB = B_SB + B_SBSZ;     // [3][64][84] bf16
constexpr int B_YBSZ = 3 * 64 * 84 * 2; // 32256
constexpr int B_SMEM = B_YB + B_YBSZ;   // 62976 -> 2 blocks/CU
static_assert(B_SMEM <= 81920, "B LDS over 2-block budget");

// ---------- workspace ----------
constexpr size_t WSO_FCW = 0;                           // [64][2880] bf16 m'=t*64+o
constexpr size_t WSO_W2F = WSO_FCW + 64 * FCIN * 2;     // [3][32][32] bf16
constexpr size_t WSO_W3F = WSO_W2F + 3 * 32 * 32 * 2;   // [5][64][32] bf16
constexpr size_t WSO_UB  = WSO_W3F + 5 * 64 * 32 * 2;   // [3][80][96] bf16 sym-folded
constexpr size_t WSO_W1F = WSO_UB + 3 * 80 * 96 * 2;    // [16][32] bf16
constexpr size_t WS_WEIGHTS = WSO_W1F + 16 * 32 * 2;    // 442368
constexpr size_t WSO_C3 = WS_WEIGHTS;                   // [B][2888] bf16 linear

__device__ __forceinline__ short f2b(float f) {
    return (short)__builtin_bit_cast(unsigned short, __float2bfloat16(f));
}
__device__ __forceinline__ float b2f(short s) {
    unsigned int u = ((unsigned int)(unsigned short)s) << 16;
    return __builtin_bit_cast(float, u);
}
__device__ __forceinline__ bf16x8 ld_frag8(const char* p) {
    union { bf16x8 v; short4v h[2]; } u;
    u.h[0] = *(const short4v*)(p);
    u.h[1] = *(const short4v*)(p + 8);
    return u.v;
}

__global__ __launch_bounds__(256) void pre_convert(
    const float* __restrict__ fcw, const float* __restrict__ w2,
    const float* __restrict__ w3, const float* __restrict__ w1,
    const float* __restrict__ sw, char* __restrict__ ws) {
    int idx = blockIdx.x * 256 + threadIdx.x;
    if (idx < 64 * FCIN) {
        int j = idx / FCIN, mp = idx % FCIN;
        int o = mp & 63, t = mp >> 6;
        ((short*)(ws + WSO_FCW))[idx] = f2b(fcw[j * FCIN + o * 45 + t]);
    }
    if (idx < 3 * 32 * 32) {
        int p = idx >> 10, o = (idx >> 5) & 31, k32 = idx & 31;
        int kk = 2 * p + (k32 >> 4), ic = k32 & 15;
        float v = (kk < 5) ? w2[(o * 16 + ic) * 5 + kk] : 0.f;
        ((short*)(ws + WSO_W2F))[idx] = f2b(v);
    }
    if (idx < 5 * 64 * 32) {
        int kk = idx >> 11, o = (idx >> 5) & 63, ic = idx & 31;
        ((short*)(ws + WSO_W3F))[idx] = f2b(w3[(o * 32 + ic) * 5 + kk]);
    }
    if (idx < 3 * 80 * 96) {
        int r = idx / (80 * 96), rem = idx % (80 * 96), nn = rem / 96, kk = rem % 96;
        float v = 0.f;
        if (nn < 68 && kk < 68) {
            if (nn == 67 && kk == 67) v = sw[r * LIB];
            else if (nn == 67) v = 0.5f * sw[r * LIB + 1 + kk];
            else if (kk == 67) v = 0.5f * sw[r * LIB + 1 + nn];
            else {
                int a = nn < kk ? nn : kk, b = nn < kk ? kk : nn;
                int q = a * 67 - (a * (a - 1)) / 2 + (b - a);
                v = sw[r * LIB + 68 + q];
                if (nn != kk) v *= 0.5f;
            }
        }
        ((short*)(ws + WSO_UB))[idx] = f2b(v);
    }
    if (idx < 512) {
        int o = idx >> 5, k = idx & 31;
        ((short*)(ws + WSO_W1F))[idx] = (k < 5) ? f2b(w1[o * 5 + k]) : (short)0;
    }
}

// =================== KERNEL A: conv pipeline, 8 samples/block ===================
__global__ __launch_bounds__(512, 2) void conv_pipe(
    const float* __restrict__ lidar, const float* __restrict__ b1,
    const float* __restrict__ b2, const float* __restrict__ b3,
    char* __restrict__ ws)
{
    __shared__ char smem[A_SMEM];
    const int tid = threadIdx.x;
    const int wv = tid >> 6, lane = tid & 63;
    const int lr = lane & 15, lg = lane >> 4;
    const long blk = blockIdx.x;
    float* par = (float*)(smem + A_PAR);
    short* xb = (short*)(smem + A_XB);

    const int sW = wv & 1;              // sample-in-group (2/group)
    const int qW = wv >> 1;             // 0..3
    const int o0_2 = (qW >> 1) * 16;
    const int o0_3 = qW * 16;

    // weight fragments (ws guaranteed by launcher)
    bf16x8 af1 = *(const bf16x8*)(ws + WSO_W1F + (lr * 32 + lg * 8) * 2);
    bf16x8 af2[3], af3[5];
    #pragma unroll
    for (int p = 0; p < 3; p++)
        af2[p] = *(const bf16x8*)(ws + WSO_W2F + ((p * 32 + o0_2 + lr) * 32 + lg * 8) * 2);
    #pragma unroll
    for (int kk = 0; kk < 5; kk++)
        af3[kk] = *(const bf16x8*)(ws + WSO_W3F + ((kk * 64 + o0_3 + lr) * 32 + lg * 8) * 2);

    auto stage_xb = [&](int g) {   // tid<180: 2 samples' lidar -> bf16
        float4v v = ((const float4v*)(lidar + (blk * 8 + g * 2) * L0))[tid];
        int si = tid / 90, c = tid % 90;
        short* dst = xb + si * XB_STRIDE + 2 + 4 * c;
        *(int*)(dst) = (int)(unsigned short)f2b(v[0]) | ((int)(unsigned short)f2b(v[1]) << 16);
        *(int*)(dst + 2) = (int)(unsigned short)f2b(v[2]) | ((int)(unsigned short)f2b(v[3]) << 16);
    };

    // ---- P0 ----
    if (tid < 16) par[tid] = b1[tid];
    else if (tid < 48) par[16 + tid - 16] = b2[tid - 16];
    else if (tid < 112) par[48 + tid - 48] = b3[tid - 48];
    if (tid >= 120 && tid < 124) {
        int s = (tid - 120) >> 1, h = (tid - 120) & 1;
        ((int*)xb)[s * (XB_STRIDE / 2) + (h ? 181 : 0)] = 0;
    }
    if (tid >= 128 && tid < 208) {
        int i = tid - 128, slot = i / 40, r = i % 40;
        const int rows[4] = {2, 3, 184, 185};
        *(int*)(smem + A_C1 + slot * S1B + rows[r / 10] * (C1_CH * 2) + (r % 10) * 4) = 0;
    }
    if (tid >= 208 && tid < 384) {
        int i = tid - 208, slot = i / 88, r = i % 88;
        const int rows[4] = {2, 3, 94, 95};
        *(int*)(smem + A_C2 + slot * S2B + rows[r / 22] * (C2_CH * 2) + (r % 22) * 4) = 0;
    }
    if (tid < 180) stage_xb(0);
    __syncthreads();

    float bia1_[4], bia2_[4], bia3_[4];
    #pragma unroll
    for (int r = 0; r < 4; r++) {
        bia1_[r] = par[lg * 4 + r];
        bia2_[r] = par[16 + o0_2 + lg * 4 + r];
        bia3_[r] = par[48 + o0_3 + lg * 4 + r];
    }

    auto conv1_body = [&]() {
        const short* xs = xb + sW * XB_STRIDE;
        char* c1s = smem + A_C1 + sW * S1B;
        #pragma unroll
        for (int i = 0; i < 3; ++i) {
            const int t = (qW * 3 + i) * 16 + lr;
            bf16x8 bv = {0, 0, 0, 0, 0, 0, 0, 0};
            if (lg == 0) {
                const short* xp = xs + 2 * t;
                int d0 = *(const int*)(xp);
                int d1 = *(const int*)(xp + 2);
                bv[0] = (short)(d0 & 0xffff); bv[1] = (short)(d0 >> 16);
                bv[2] = (short)(d1 & 0xffff); bv[3] = (short)(d1 >> 16);
                bv[4] = xp[4];
            }
            f32x4 acc = {0.f, 0.f, 0.f, 0.f};
            acc = __builtin_amdgcn_mfma_f32_16x16x32_bf16(af1, bv, acc, 0, 0, 0);
            if (t < 180) {
                short4v pk = { f2b(fmaxf(acc[0] + bia1_[0], 0.f)), f2b(fmaxf(acc[1] + bia1_[1], 0.f)),
                               f2b(fmaxf(acc[2] + bia1_[2], 0.f)), f2b(fmaxf(acc[3] + bia1_[3], 0.f)) };
                *(short4v*)(c1s + (t + 4) * (C1_CH * 2) + lg * 8) = pk;
            }
        }
    };

    conv1_body();
    __syncthreads();

    auto dump_c3 = [&](int gdone) {    // LDS c3 (swizzled) -> global linear, coalesced 16B
        for (int i4 = tid; i4 < 722; i4 += 512) {
            int sample = i4 / 361, w16 = i4 % 361;
            int wb = w16 * 16, tw = wb >> 7;
            int4v v = *(const int4v*)(smem + A_C3 + sample * (S3E * 2) + (wb ^ ((tw & 7) << 4)));
            long nidx = blk * 8 + gdone * 2 + sample;
            ((int4v*)(ws + WSO_C3))[nidx * 361 + w16] = v;
        }
    };

    for (int g = 0; g < 4; ++g) {
        // ---- C2(g) + dump(g-1) + stage lidar(g+1) ----
        {
            const int orow = o0_2 + lg * 4;
            const int kkp = lane >> 5, i0 = (lg & 1) * 8;
            const char* bp = smem + A_C1 + sW * S1B
                           + (2 * lr + kkp + 2) * (C1_CH * 2) + i0 * 2
                           + (qW & 1) * 3840;
            char* c2s = smem + A_C2 + sW * S2B;
            const bool stg = (g < 3) && (tid < 180);
            float4v lv;
            if (stg) lv = ((const float4v*)(lidar + (blk * 8 + (g + 1) * 2) * L0))[tid];
            #pragma unroll
            for (int i = 0; i < 3; ++i) {
                f32x4 acc = {0.f, 0.f, 0.f, 0.f};
                #pragma unroll
                for (int p = 0; p < 3; p++) {
                    bf16x8 bf = ld_frag8(bp + i * 1280 + p * 80);
                    acc = __builtin_amdgcn_mfma_f32_16x16x32_bf16(af2[p], bf, acc, 0, 0, 0);
                }
                const int tw = ((qW & 1) * 3 + i) * 16 + lr;
                if (tw < L2n) {
                    short4v pk = { f2b(fmaxf(acc[0] + bia2_[0], 0.f)), f2b(fmaxf(acc[1] + bia2_[1], 0.f)),
                                   f2b(fmaxf(acc[2] + bia2_[2], 0.f)), f2b(fmaxf(acc[3] + bia2_[3], 0.f)) };
                    *(short4v*)(c2s + (tw + 4) * (C2_CH * 2) + orow * 2) = pk;
                }
            }
            if (g > 0) dump_c3(g - 1);
            if (stg) {
                int si = tid / 90, c = tid % 90;
                short* dst = xb + si * XB_STRIDE + 2 + 4 * c;
                *(int*)(dst) = (int)(unsigned short)f2b(lv[0]) | ((int)(unsigned short)f2b(lv[1]) << 16);
                *(int*)(dst + 2) = (int)(unsigned short)f2b(lv[2]) | ((int)(unsigned short)f2b(lv[3]) << 16);
            }
        }
        __syncthreads();

        // ---- C3(g) -> LDS c3 (swizzled) + C1(g+1) ----
        {
            const int orow = o0_3 + lg * 4;
            const char* bp2 = smem + A_C2 + sW * S2B
                            + (2 * lr + 2) * (C2_CH * 2) + lg * 16;
            char* c3s = smem + A_C3 + sW * (S3E * 2);
            #pragma unroll
            for (int tt = 0; tt < 3; ++tt) {
                f32x4 acc = {0.f, 0.f, 0.f, 0.f};
                #pragma unroll
                for (int kk = 0; kk < 5; kk++) {
                    bf16x8 bf = ld_frag8(bp2 + tt * 2816 + kk * 88);
                    acc = __builtin_amdgcn_mfma_f32_16x16x32_bf16(af3[kk], bf, acc, 0, 0, 0);
                }
                const int tw = tt * 16 + lr;
                if (tw < L3n) {
                    short4v pk = { f2b(fmaxf(acc[0] + bia3_[0], 0.f)), f2b(fmaxf(acc[1] + bia3_[1], 0.f)),
                                   f2b(fmaxf(acc[2] + bia3_[2], 0.f)), f2b(fmaxf(acc[3] + bia3_[3], 0.f)) };
                    int byteoff = (tw * 64 + orow) * 2;
                    byteoff ^= (tw & 7) << 4;
                    *(short4v*)(c3s + byteoff) = pk;
                }
            }
            if (g < 3) conv1_body();
        }
        __syncthreads();
    }
    dump_c3(3);
}

// =================== KERNEL B: fc + quad + tail, 64 samples/block ===================
__global__ __launch_bounds__(512, 2) void fc_tail(
    const float* __restrict__ odom, const float* __restrict__ fcb,
    const float* __restrict__ sw, const char* __restrict__ ws,
    float* __restrict__ out)
{
    __shared__ char smem[B_SMEM];
    const int tid = threadIdx.x;
    const int wv = tid >> 6, lane = tid & 63;
    const int lr = lane & 15, lg = lane >> 4;
    const long blk = blockIdx.x;
    const long sbase = blk * 64;
    const short* c3g = (const short*)(ws + WSO_C3);
    const short* fcwb = (const short*)(ws + WSO_FCW);
    float* st = (float*)(smem + B_ST);
    short* sb = (short*)(smem + B_SB);
    short* yb = (short*)(smem + B_YB);

    // ---- FC: M=64, N=64, K=2880 ; wave=(jt, mh), full K, no reduce ----
    {
        const int jt = wv & 3, mh = wv >> 2, j0 = jt * 16;
        const float fj = fcb[j0 + lr];
        const short* brow = fcwb + (long)(j0 + lr) * FCIN + lg * 8;
        #pragma unroll
        for (int mt = 0; mt < 2; ++mt) {
            const int sb0 = mh * 32 + mt * 16;
            const short* arow = c3g + (sbase + sb0 + lr) * S3E + lg * 8;
            f32x4 acc = {0.f, 0.f, 0.f, 0.f};
            bf16x8 a0 = *(const bf16x8*)(arow);
            bf16x8 b0 = *(const bf16x8*)(brow);
            for (int kt = 0; kt < 90; ++kt) {
                bf16x8 ac = a0, bc = b0;
                if (kt < 89) {
                    a0 = *(const bf16x8*)(arow + (kt + 1) * 32);
                    b0 = *(const bf16x8*)(brow + (kt + 1) * 32);
                }
                acc = __builtin_amdgcn_mfma_f32_16x16x32_bf16(ac, bc, acc, 0, 0, 0);
            }
            #pragma unroll
            for (int r = 0; r < 4; ++r)
                st[(sb0 + lg * 4 + r) * 68 + j0 + lr] = acc[r] + fj;
        }
    }
    __syncthreads();

    // ---- sbf fill: [64][104] bf16 = state | odom | 1 | pad ----
    for (int i = tid; i < 64 * 104; i += 512) {
        int sr = i / 104, c = i % 104;
        short v;
        if (c < 64) v = f2b(st[sr * 68 + c]);
        else if (c < 67) v = f2b(odom[(sbase + sr) * 3 + (c - 64)]);
        else if (c == 67) v = (short)0x3F80;
        else v = 0;
        sb[i] = v;
    }
    __syncthreads();

    // ---- quad GEMM: Y_r = S * Ub_r^T ; 15 jobs over 8 waves, M=64 ----
    {
        const short* ubb = (const short*)(ws + WSO_UB);
        for (int job = wv; job < 15; job += 8) {
            const int r = job / 5, nt = job % 5;
            const short* ub = ubb + (r * 80 + nt * 16 + lr) * 96 + lg * 8;
            #pragma unroll
            for (int mt = 0; mt < 4; ++mt) {
                f32x4 acc = {0.f, 0.f, 0.f, 0.f};
                #pragma unroll
                for (int kt = 0; kt < 3; ++kt) {
                    bf16x8 av = *(const bf16x8*)(sb + (mt * 16 + lr) * 104 + kt * 32 + lg * 8);
                    bf16x8 bv = *(const bf16x8*)(ub + kt * 32);
                    acc = __builtin_amdgcn_mfma_f32_16x16x32_bf16(av, bv, acc, 0, 0, 0);
                }
                #pragma unroll
                for (int rr = 0; rr < 4; ++rr)
                    yb[(r * 64 + mt * 16 + lg * 4 + rr) * 84 + nt * 16 + lr] = f2b(acc[rr]);
            }
        }
    }
    __syncthreads();

    // ---- dot + trig: wave = 8 samples ----
    for (int ss = 0; ss < 8; ++ss) {
        const int sr = wv * 8 + ss;
        const long n = sbase + sr;
        float sv = st[sr * 68 + lane];
        float sn = __sinf(sv), cs = __cosf(sv);
        float d0 = sw[2346 + lane] * sn + sw[2413 + lane] * cs
                 + b2f(yb[(0 * 64 + sr) * 84 + lane]) * sv;
        float d1 = sw[LIB + 2346 + lane] * sn + sw[LIB + 2413 + lane] * cs
                 + b2f(yb[(1 * 64 + sr) * 84 + lane]) * sv;
        float d2 = sw[2 * LIB + 2346 + lane] * sn + sw[2 * LIB + 2413 + lane] * cs
                 + b2f(yb[(2 * 64 + sr) * 84 + lane]) * sv;
        if (lane < 3) {
            float ov = odom[n * 3 + lane];
            float sn2 = __sinf(ov), cs2 = __cosf(ov);
            int j2 = 64 + lane;
            d0 += sw[2346 + j2] * sn2 + sw[2413 + j2] * cs2 + b2f(yb[(0 * 64 + sr) * 84 + j2]) * ov;
            d1 += sw[LIB + 2346 + j2] * sn2 + sw[LIB + 2413 + j2] * cs2 + b2f(yb[(1 * 64 + sr) * 84 + j2]) * ov;
            d2 += sw[2 * LIB + 2346 + j2] * sn2 + sw[2 * LIB + 2413 + j2] * cs2 + b2f(yb[(2 * 64 + sr) * 84 + j2]) * ov;
        } else if (lane == 3) {
            d0 += b2f(yb[(0 * 64 + sr) * 84 + 67]);
            d1 += b2f(yb[(1 * 64 + sr) * 84 + 67]);
            d2 += b2f(yb[(2 * 64 + sr) * 84 + 67]);
        }
        #pragma unroll
        for (int off = 32; off; off >>= 1) {
            d0 += __shfl_xor(d0, off, 64);
            d1 += __shfl_xor(d1, off, 64);
            d2 += __shfl_xor(d2, off, 64);
        }
        if (lane == 0) {
            out[n * 3 + 0] = odom[n * 3 + 0] + 0.1f * d0;
            out[n * 3 + 1] = odom[n * 3 + 1] + 0.1f * d1;
            out[n * 3 + 2] = odom[n * 3 + 2] + 0.1f * d2;
        }
    }
}

extern "C" void kernel_launch(void* const* d_in, const int* in_sizes, int n_in,
                              void* d_out, int out_size, void* d_ws, size_t ws_size,
                              hipStream_t stream) {
    const float* lidar = (const float*)d_in[0];
    const float* odom  = (const float*)d_in[1];
    const float* w1    = (const float*)d_in[2];
    const float* b1    = (const float*)d_in[3];
    const float* w2    = (const float*)d_in[4];
    const float* b2    = (const float*)d_in[5];
    const float* w3    = (const float*)d_in[6];
    const float* b3    = (const float*)d_in[7];
    const float* fcw   = (const float*)d_in[8];
    const float* fcb   = (const float*)d_in[9];
    const float* sw    = (const float*)d_in[10];
    float* out = (float*)d_out;

    int B = in_sizes[0] / L0;                              // 32768
    size_t ws_total = WSO_C3 + (size_t)B * S3E * 2;        // ~189.6 MB (R8 confirmed available)
    if (ws_size < ws_total) return;                        // visible failure rather than corruption

    char* ws = (char*)d_ws;
    pre_convert<<<(64 * FCIN + 255) / 256, 256, 0, stream>>>(fcw, w2, w3, w1, sw, ws);
    conv_pipe<<<B / 8, 512, 0, stream>>>(lidar, b1, b2, b3, ws);
    fc_tail<<<B / 64, 512, 0, stream>>>(odom, fcb, sw, ws, out);
}

// Round 15
// 194.655 us; speedup vs baseline: 1.2647x; 1.2647x over previous
//
#include <hip/hip_runtime.h>
#include <hip/hip_bf16.h>

typedef __attribute__((ext_vector_type(8))) short bf16x8;
typedef __attribute__((ext_vector_type(4))) short short4v;
typedef __attribute__((ext_vector_type(4))) float f32x4;
typedef __attribute__((ext_vector_type(4))) float float4v;
typedef __attribute__((ext_vector_type(4))) int int4v;

constexpr int L0 = 360, L2n = 90, L3n = 45;
constexpr int SD = 67, NQ = 2278, LIB = 2480, FCIN = 2880;
constexpr int C1_CH = 20, S1B = 186 * C1_CH * 2;   // 7440
constexpr int C2_CH = 44, S2B = 96 * C2_CH * 2;    // 8448
constexpr int S3E = 2888;                          // c3 elems/sample (45*64 + pad)
constexpr int XB_STRIDE = 392;

// ---------- kernel A LDS: all 8 samples' c3 resident ----------
constexpr int A_C3 = 0;                    // [8][2888] bf16, XOR-swizzled per sample
constexpr int A_C3SZ = 8 * S3E * 2;        // 46208
constexpr int A_C1 = A_C3 + A_C3SZ;        // 46208
constexpr int A_C1SZ = 2 * S1B;            // 14880
constexpr int A_C2 = A_C1 + A_C1SZ;        // 61088
constexpr int A_C2SZ = 2 * S2B + 512;      // 17408
constexpr int A_XB = A_C2 + A_C2SZ;        // 78496
constexpr int A_XBSZ = 2 * XB_STRIDE * 2;  // 1568
constexpr int A_PAR = A_XB + A_XBSZ;       // 80064
constexpr int A_SMEM = A_PAR + 448;        // 80512 -> 2 blocks/CU
static_assert(A_SMEM <= 81920, "A LDS over 2-block budget");

// ---------- kernel B LDS ----------
constexpr int B_ST = 0;                 // [64][68] f32
constexpr int B_STSZ = 64 * 68 * 4;     // 17408
constexpr int B_SB = B_ST + B_STSZ;     // [64][104] bf16
constexpr int B_SBSZ = 64 * 104 * 2;    // 13312
constexpr int B_YB = B_SB + B_SBSZ;     // [3][64][84] bf16
constexpr int B_YBSZ = 3 * 64 * 84 * 2; // 32256
constexpr int B_SMEM = B_YB + B_YBSZ;   // 62976 -> 2 blocks/CU
static_assert(B_SMEM <= 81920, "B LDS over 2-block budget");

// ---------- workspace ----------
constexpr size_t WSO_FCW = 0;                           // [64][2880] bf16 m'=t*64+o
constexpr size_t WSO_W2F = WSO_FCW + 64 * FCIN * 2;
constexpr size_t WSO_W3F = WSO_W2F + 3 * 32 * 32 * 2;
constexpr size_t WSO_UB  = WSO_W3F + 5 * 64 * 32 * 2;
constexpr size_t WSO_W1F = WSO_UB + 3 * 80 * 96 * 2;
constexpr size_t WS_WEIGHTS = WSO_W1F + 16 * 32 * 2;    // 442368
constexpr size_t WSO_C3 = WS_WEIGHTS;                   // [B/8][361][8][8] bf16 (k8-interleaved)

__device__ __forceinline__ short f2b(float f) {
    return (short)__builtin_bit_cast(unsigned short, __float2bfloat16(f));
}
__device__ __forceinline__ float b2f(short s) {
    unsigned int u = ((unsigned int)(unsigned short)s) << 16;
    return __builtin_bit_cast(float, u);
}
__device__ __forceinline__ bf16x8 ld_frag8(const char* p) {
    union { bf16x8 v; short4v h[2]; } u;
    u.h[0] = *(const short4v*)(p);
    u.h[1] = *(const short4v*)(p + 8);
    return u.v;
}

__global__ __launch_bounds__(256) void pre_convert(
    const float* __restrict__ fcw, const float* __restrict__ w2,
    const float* __restrict__ w3, const float* __restrict__ w1,
    const float* __restrict__ sw, char* __restrict__ ws) {
    int idx = blockIdx.x * 256 + threadIdx.x;
    if (idx < 64 * FCIN) {
        int j = idx / FCIN, mp = idx % FCIN;
        int o = mp & 63, t = mp >> 6;
        ((short*)(ws + WSO_FCW))[idx] = f2b(fcw[j * FCIN + o * 45 + t]);
    }
    if (idx < 3 * 32 * 32) {
        int p = idx >> 10, o = (idx >> 5) & 31, k32 = idx & 31;
        int kk = 2 * p + (k32 >> 4), ic = k32 & 15;
        float v = (kk < 5) ? w2[(o * 16 + ic) * 5 + kk] : 0.f;
        ((short*)(ws + WSO_W2F))[idx] = f2b(v);
    }
    if (idx < 5 * 64 * 32) {
        int kk = idx >> 11, o = (idx >> 5) & 63, ic = idx & 31;
        ((short*)(ws + WSO_W3F))[idx] = f2b(w3[(o * 32 + ic) * 5 + kk]);
    }
    if (idx < 3 * 80 * 96) {
        int r = idx / (80 * 96), rem = idx % (80 * 96), nn = rem / 96, kk = rem % 96;
        float v = 0.f;
        if (nn < 68 && kk < 68) {
            if (nn == 67 && kk == 67) v = sw[r * LIB];
            else if (nn == 67) v = 0.5f * sw[r * LIB + 1 + kk];
            else if (kk == 67) v = 0.5f * sw[r * LIB + 1 + nn];
            else {
                int a = nn < kk ? nn : kk, b = nn < kk ? kk : nn;
                int q = a * 67 - (a * (a - 1)) / 2 + (b - a);
                v = sw[r * LIB + 68 + q];
                if (nn != kk) v *= 0.5f;
            }
        }
        ((short*)(ws + WSO_UB))[idx] = f2b(v);
    }
    if (idx < 512) {
        int o = idx >> 5, k = idx & 31;
        ((short*)(ws + WSO_W1F))[idx] = (k < 5) ? f2b(w1[o * 5 + k]) : (short)0;
    }
}

// =================== KERNEL A: conv pipeline, 8 samples/block ===================
__global__ __launch_bounds__(512, 2) void conv_pipe(
    const float* __restrict__ lidar, const float* __restrict__ b1,
    const float* __restrict__ b2, const float* __restrict__ b3,
    char* __restrict__ ws)
{
    __shared__ char smem[A_SMEM];
    const int tid = threadIdx.x;
    const int wv = tid >> 6, lane = tid & 63;
    const int lr = lane & 15, lg = lane >> 4;
    const long blk = blockIdx.x;
    float* par = (float*)(smem + A_PAR);
    short* xb = (short*)(smem + A_XB);

    const int sW = wv & 1;
    const int qW = wv >> 1;
    const int o0_2 = (qW >> 1) * 16;
    const int o0_3 = qW * 16;

    bf16x8 af1 = *(const bf16x8*)(ws + WSO_W1F + (lr * 32 + lg * 8) * 2);
    bf16x8 af2[3], af3[5];
    #pragma unroll
    for (int p = 0; p < 3; p++)
        af2[p] = *(const bf16x8*)(ws + WSO_W2F + ((p * 32 + o0_2 + lr) * 32 + lg * 8) * 2);
    #pragma unroll
    for (int kk = 0; kk < 5; kk++)
        af3[kk] = *(const bf16x8*)(ws + WSO_W3F + ((kk * 64 + o0_3 + lr) * 32 + lg * 8) * 2);

    auto stage_xb = [&](int g) {
        float4v v = ((const float4v*)(lidar + (blk * 8 + g * 2) * L0))[tid];
        int si = tid / 90, c = tid % 90;
        short* dst = xb + si * XB_STRIDE + 2 + 4 * c;
        *(int*)(dst) = (int)(unsigned short)f2b(v[0]) | ((int)(unsigned short)f2b(v[1]) << 16);
        *(int*)(dst + 2) = (int)(unsigned short)f2b(v[2]) | ((int)(unsigned short)f2b(v[3]) << 16);
    };

    // ---- P0 ----
    if (tid < 16) par[tid] = b1[tid];
    else if (tid < 48) par[16 + tid - 16] = b2[tid - 16];
    else if (tid < 112) par[48 + tid - 48] = b3[tid - 48];
    if (tid >= 120 && tid < 124) {
        int s = (tid - 120) >> 1, h = (tid - 120) & 1;
        ((int*)xb)[s * (XB_STRIDE / 2) + (h ? 181 : 0)] = 0;
    }
    if (tid >= 128 && tid < 208) {
        int i = tid - 128, slot = i / 40, r = i % 40;
        const int rows[4] = {2, 3, 184, 185};
        *(int*)(smem + A_C1 + slot * S1B + rows[r / 10] * (C1_CH * 2) + (r % 10) * 4) = 0;
    }
    if (tid >= 208 && tid < 384) {
        int i = tid - 208, slot = i / 88, r = i % 88;
        const int rows[4] = {2, 3, 94, 95};
        *(int*)(smem + A_C2 + slot * S2B + rows[r / 22] * (C2_CH * 2) + (r % 22) * 4) = 0;
    }
    if (tid < 180) stage_xb(0);
    __syncthreads();

    float bia1_[4], bia2_[4], bia3_[4];
    #pragma unroll
    for (int r = 0; r < 4; r++) {
        bia1_[r] = par[lg * 4 + r];
        bia2_[r] = par[16 + o0_2 + lg * 4 + r];
        bia3_[r] = par[48 + o0_3 + lg * 4 + r];
    }

    auto conv1_body = [&]() {
        const short* xs = xb + sW * XB_STRIDE;
        char* c1s = smem + A_C1 + sW * S1B;
        #pragma unroll
        for (int i = 0; i < 3; ++i) {
            const int t = (qW * 3 + i) * 16 + lr;
            bf16x8 bv = {0, 0, 0, 0, 0, 0, 0, 0};
            if (lg == 0) {
                const short* xp = xs + 2 * t;
                int d0 = *(const int*)(xp);
                int d1 = *(const int*)(xp + 2);
                bv[0] = (short)(d0 & 0xffff); bv[1] = (short)(d0 >> 16);
                bv[2] = (short)(d1 & 0xffff); bv[3] = (short)(d1 >> 16);
                bv[4] = xp[4];
            }
            f32x4 acc = {0.f, 0.f, 0.f, 0.f};
            acc = __builtin_amdgcn_mfma_f32_16x16x32_bf16(af1, bv, acc, 0, 0, 0);
            if (t < 180) {
                short4v pk = { f2b(fmaxf(acc[0] + bia1_[0], 0.f)), f2b(fmaxf(acc[1] + bia1_[1], 0.f)),
                               f2b(fmaxf(acc[2] + bia1_[2], 0.f)), f2b(fmaxf(acc[3] + bia1_[3], 0.f)) };
                *(short4v*)(c1s + (t + 4) * (C1_CH * 2) + lg * 8) = pk;
            }
        }
    };

    conv1_body();
    __syncthreads();

    for (int g = 0; g < 4; ++g) {
        // ---- C2(g) + stage lidar(g+1) ----
        {
            const int orow = o0_2 + lg * 4;
            const int kkp = lane >> 5, i0 = (lg & 1) * 8;
            const char* bp = smem + A_C1 + sW * S1B
                           + (2 * lr + kkp + 2) * (C1_CH * 2) + i0 * 2
                           + (qW & 1) * 3840;
            char* c2s = smem + A_C2 + sW * S2B;
            const bool stg = (g < 3) && (tid < 180);
            float4v lv;
            if (stg) lv = ((const float4v*)(lidar + (blk * 8 + (g + 1) * 2) * L0))[tid];
            #pragma unroll
            for (int i = 0; i < 3; ++i) {
                f32x4 acc = {0.f, 0.f, 0.f, 0.f};
                #pragma unroll
                for (int p = 0; p < 3; p++) {
                    bf16x8 bf = ld_frag8(bp + i * 1280 + p * 80);
                    acc = __builtin_amdgcn_mfma_f32_16x16x32_bf16(af2[p], bf, acc, 0, 0, 0);
                }
                const int tw = ((qW & 1) * 3 + i) * 16 + lr;
                if (tw < L2n) {
                    short4v pk = { f2b(fmaxf(acc[0] + bia2_[0], 0.f)), f2b(fmaxf(acc[1] + bia2_[1], 0.f)),
                                   f2b(fmaxf(acc[2] + bia2_[2], 0.f)), f2b(fmaxf(acc[3] + bia2_[3], 0.f)) };
                    *(short4v*)(c2s + (tw + 4) * (C2_CH * 2) + orow * 2) = pk;
                }
            }
            if (stg) {
                int si = tid / 90, c = tid % 90;
                short* dst = xb + si * XB_STRIDE + 2 + 4 * c;
                *(int*)(dst) = (int)(unsigned short)f2b(lv[0]) | ((int)(unsigned short)f2b(lv[1]) << 16);
                *(int*)(dst + 2) = (int)(unsigned short)f2b(lv[2]) | ((int)(unsigned short)f2b(lv[3]) << 16);
            }
        }
        __syncthreads();

        // ---- C3(g) -> LDS c3[g*2+sW] (swizzled) + C1(g+1) ----
        {
            const int orow = o0_3 + lg * 4;
            const char* bp2 = smem + A_C2 + sW * S2B
                            + (2 * lr + 2) * (C2_CH * 2) + lg * 16;
            char* c3s = smem + A_C3 + (g * 2 + sW) * (S3E * 2);
            #pragma unroll
            for (int tt = 0; tt < 3; ++tt) {
                f32x4 acc = {0.f, 0.f, 0.f, 0.f};
                #pragma unroll
                for (int kk = 0; kk < 5; kk++) {
                    bf16x8 bf = ld_frag8(bp2 + tt * 2816 + kk * 88);
                    acc = __builtin_amdgcn_mfma_f32_16x16x32_bf16(af3[kk], bf, acc, 0, 0, 0);
                }
                const int tw = tt * 16 + lr;
                if (tw < L3n) {
                    short4v pk = { f2b(fmaxf(acc[0] + bia3_[0], 0.f)), f2b(fmaxf(acc[1] + bia3_[1], 0.f)),
                                   f2b(fmaxf(acc[2] + bia3_[2], 0.f)), f2b(fmaxf(acc[3] + bia3_[3], 0.f)) };
                    int byteoff = (tw * 64 + orow) * 2;
                    byteoff ^= (tw & 7) << 4;
                    *(short4v*)(c3s + byteoff) = pk;
                }
            }
            if (g < 3) conv1_body();
        }
        __syncthreads();
    }

    // ---- dump all 8 samples, k8-interleaved [blk][k8][8 samples][8 elems], sample-inner ----
    for (int i4 = tid; i4 < 8 * 361; i4 += 512) {
        int k8 = i4 >> 3, sample = i4 & 7;
        int wb = k8 * 16;
        int src = wb ^ (((k8 >> 3) & 7) << 4);
        int4v v = *(const int4v*)(smem + A_C3 + sample * (S3E * 2) + src);
        ((int4v*)(ws + WSO_C3))[(blk * 361 + k8) * 8 + sample] = v;
    }
}

// =================== KERNEL B: fc + quad + tail, 64 samples/block ===================
__global__ __launch_bounds__(512, 2) void fc_tail(
    const float* __restrict__ odom, const float* __restrict__ fcb,
    const float* __restrict__ sw, const char* __restrict__ ws,
    float* __restrict__ out)
{
    __shared__ char smem[B_SMEM];
    const int tid = threadIdx.x;
    const int wv = tid >> 6, lane = tid & 63;
    const int lr = lane & 15, lg = lane >> 4;
    const long blk = blockIdx.x;
    const long sbase = blk * 64;
    const short* c3g = (const short*)(ws + WSO_C3);
    const short* fcwb = (const short*)(ws + WSO_FCW);
    float* st = (float*)(smem + B_ST);
    short* sb = (short*)(smem + B_SB);
    short* yb = (short*)(smem + B_YB);

    // ---- FC: M=64, N=64, K=2880 ; wave=(jt, mh); 2 M-tiles fused, shared B ----
    {
        const int jt = wv & 3, mh = wv >> 2, j0 = jt * 16;
        const float fj = fcb[j0 + lr];
        const short* brow = fcwb + (long)(j0 + lr) * FCIN + lg * 8;
        const int sb0 = mh * 32;
        const long n0 = sbase + sb0 + lr;
        const long n1 = n0 + 16;
        // addr(shorts) = ((n>>3)*361 + kt*4 + lg)*64 + (n&7)*8 ; per-kt stride = 256
        const short* ar0 = c3g + ((n0 >> 3) * 361 + lg) * 64 + (n0 & 7) * 8;
        const short* ar1 = c3g + ((n1 >> 3) * 361 + lg) * 64 + (n1 & 7) * 8;
        f32x4 acc0 = {0.f, 0.f, 0.f, 0.f}, acc1 = {0.f, 0.f, 0.f, 0.f};
        bf16x8 a0 = *(const bf16x8*)(ar0);
        bf16x8 a1 = *(const bf16x8*)(ar1);
        bf16x8 b0 = *(const bf16x8*)(brow);
        for (int kt = 0; kt < 90; ++kt) {
            bf16x8 ac0 = a0, ac1 = a1, bc = b0;
            if (kt < 89) {
                a0 = *(const bf16x8*)(ar0 + (kt + 1) * 256);
                a1 = *(const bf16x8*)(ar1 + (kt + 1) * 256);
                b0 = *(const bf16x8*)(brow + (kt + 1) * 32);
            }
            acc0 = __builtin_amdgcn_mfma_f32_16x16x32_bf16(ac0, bc, acc0, 0, 0, 0);
            acc1 = __builtin_amdgcn_mfma_f32_16x16x32_bf16(ac1, bc, acc1, 0, 0, 0);
        }
        #pragma unroll
        for (int r = 0; r < 4; ++r) {
            st[(sb0 + lg * 4 + r) * 68 + j0 + lr] = acc0[r] + fj;
            st[(sb0 + 16 + lg * 4 + r) * 68 + j0 + lr] = acc1[r] + fj;
        }
    }
    __syncthreads();

    // ---- sbf fill: [64][104] bf16 = state | odom | 1 | pad ----
    for (int i = tid; i < 64 * 104; i += 512) {
        int sr = i / 104, c = i % 104;
        short v;
        if (c < 64) v = f2b(st[sr * 68 + c]);
        else if (c < 67) v = f2b(odom[(sbase + sr) * 3 + (c - 64)]);
        else if (c == 67) v = (short)0x3F80;
        else v = 0;
        sb[i] = v;
    }
    __syncthreads();

    // ---- quad GEMM: Y_r = S * Ub_r^T ; 15 jobs over 8 waves, M=64 ----
    {
        const short* ubb = (const short*)(ws + WSO_UB);
        for (int job = wv; job < 15; job += 8) {
            const int r = job / 5, nt = job % 5;
            const short* ub = ubb + (r * 80 + nt * 16 + lr) * 96 + lg * 8;
            #pragma unroll
            for (int mt = 0; mt < 4; ++mt) {
                f32x4 acc = {0.f, 0.f, 0.f, 0.f};
                #pragma unroll
                for (int kt = 0; kt < 3; ++kt) {
                    bf16x8 av = *(const bf16x8*)(sb + (mt * 16 + lr) * 104 + kt * 32 + lg * 8);
                    bf16x8 bv = *(const bf16x8*)(ub + kt * 32);
                    acc = __builtin_amdgcn_mfma_f32_16x16x32_bf16(av, bv, acc, 0, 0, 0);
                }
                #pragma unroll
                for (int rr = 0; rr < 4; ++rr)
                    yb[(r * 64 + mt * 16 + lg * 4 + rr) * 84 + nt * 16 + lr] = f2b(acc[rr]);
            }
        }
    }
    __syncthreads();

    // ---- dot + trig: wave = 8 samples ----
    for (int ss = 0; ss < 8; ++ss) {
        const int sr = wv * 8 + ss;
        const long n = sbase + sr;
        float sv = st[sr * 68 + lane];
        float sn = __sinf(sv), cs = __cosf(sv);
        float d0 = sw[2346 + lane] * sn + sw[2413 + lane] * cs
                 + b2f(yb[(0 * 64 + sr) * 84 + lane]) * sv;
        float d1 = sw[LIB + 2346 + lane] * sn + sw[LIB + 2413 + lane] * cs
                 + b2f(yb[(1 * 64 + sr) * 84 + lane]) * sv;
        float d2 = sw[2 * LIB + 2346 + lane] * sn + sw[2 * LIB + 2413 + lane] * cs
                 + b2f(yb[(2 * 64 + sr) * 84 + lane]) * sv;
        if (lane < 3) {
            float ov = odom[n * 3 + lane];
            float sn2 = __sinf(ov), cs2 = __cosf(ov);
            int j2 = 64 + lane;
            d0 += sw[2346 + j2] * sn2 + sw[2413 + j2] * cs2 + b2f(yb[(0 * 64 + sr) * 84 + j2]) * ov;
            d1 += sw[LIB + 2346 + j2] * sn2 + sw[LIB + 2413 + j2] * cs2 + b2f(yb[(1 * 64 + sr) * 84 + j2]) * ov;
            d2 += sw[2 * LIB + 2346 + j2] * sn2 + sw[2 * LIB + 2413 + j2] * cs2 + b2f(yb[(2 * 64 + sr) * 84 + j2]) * ov;
        } else if (lane == 3) {
            d0 += b2f(yb[(0 * 64 + sr) * 84 + 67]);
            d1 += b2f(yb[(1 * 64 + sr) * 84 + 67]);
            d2 += b2f(yb[(2 * 64 + sr) * 84 + 67]);
        }
        #pragma unroll
        for (int off = 32; off; off >>= 1) {
            d0 += __shfl_xor(d0, off, 64);
            d1 += __shfl_xor(d1, off, 64);
            d2 += __shfl_xor(d2, off, 64);
        }
        if (lane == 0) {
            out[n * 3 + 0] = odom[n * 3 + 0] + 0.1f * d0;
            out[n * 3 + 1] = odom[n * 3 + 1] + 0.1f * d1;
            out[n * 3 + 2] = odom[n * 3 + 2] + 0.1f * d2;
        }
    }
}

extern "C" void kernel_launch(void* const* d_in, const int* in_sizes, int n_in,
                              void* d_out, int out_size, void* d_ws, size_t ws_size,
                              hipStream_t stream) {
    const float* lidar = (const float*)d_in[0];
    const float* odom  = (const float*)d_in[1];
    const float* w1    = (const float*)d_in[2];
    const float* b1    = (const float*)d_in[3];
    const float* w2    = (const float*)d_in[4];
    const float* b2    = (const float*)d_in[5];
    const float* w3    = (const float*)d_in[6];
    const float* b3    = (const float*)d_in[7];
    const float* fcw   = (const float*)d_in[8];
    const float* fcb   = (const float*)d_in[9];
    const float* sw    = (const float*)d_in[10];
    float* out = (float*)d_out;

    int B = in_sizes[0] / L0;                              // 32768
    size_t ws_total = WSO_C3 + (size_t)B * S3E * 2;        // ~189.6 MB
    if (ws_size < ws_total) return;

    char* ws = (char*)d_ws;
    pre_convert<<<(64 * FCIN + 255) / 256, 256, 0, stream>>>(fcw, w2, w3, w1, sw, ws);
    conv_pipe<<<B / 8, 512, 0, stream>>>(lidar, b1, b2, b3, ws);
    fc_tail<<<B / 64, 512, 0, stream>>>(odom, fcb, sw, ws, out);
}